// Round 2
// baseline (715.839 us; speedup 1.0000x reference)
//
#include <hip/hip_runtime.h>

// Fused Conv3x3(8->64) + bias + GroupNorm(16) + scale + MaxPool4x4 + clamp
// Block = (batch, group). Thread = (channel c=t&3, row-half rh=(t>>2)&1,
// col-group cg=t>>3 covering cols 4cg..4cg+3). Weights live in registers
// (72/thread). Pool commutes with the per-channel affine: since
// sign(A_c)=sign(gnw_c*scale_c) is known up-front (rsqrt>0), keep only the
// max (A>=0) or min (A<0) of the raw conv output per 4x4 window.

constexpr int CI   = 8;
constexpr int CO   = 64;
constexpr int HIN  = 128;
constexpr int WIN_ = 128;
constexpr int HO_  = 126;
constexpr int CPG  = 4;    // channels per group
constexpr int PW   = 31;   // pooled H/W
constexpr float EPS = 1e-5f;

__global__ __launch_bounds__(256, 3)
void fused_conv_gn_pool(const float* __restrict__ x,
                        const float* __restrict__ cw,
                        const float* __restrict__ cb,
                        const float* __restrict__ gnw,
                        const float* __restrict__ gnb,
                        const float* __restrict__ scl,
                        float* __restrict__ out)
{
    __shared__ float xb[6][CI][WIN_];        // rolling input rows  24576 B
    __shared__ float wpool[CPG][PW][PW];     // window extremes     15376 B
    __shared__ float redbuf[4][2];
    __shared__ float statbuf[2];

    const int t   = threadIdx.x;
    const int b   = blockIdx.x >> 4;
    const int g   = blockIdx.x & 15;
    const int co0 = g * CPG;

    const int c    = t & 3;          // channel within group
    const int rh   = (t >> 2) & 1;   // which row-pair of the 4-row window
    const int cg   = t >> 3;         // col group: cols 4cg..4cg+3
    const int col0 = cg * 4;
    const int co   = co0 + c;

    // ---- per-thread channel weights in registers (72 floats, contiguous) ----
    float w[72];
    {
        const float4* wp4 = (const float4*)(cw + (size_t)co * (CI * 9));
        #pragma unroll
        for (int i = 0; i < 18; ++i) ((float4*)w)[i] = wp4[i];
    }
    const float bias = cb[co];
    const bool  pos  = (gnw[co] * scl[co] >= 0.f);   // keep max if true, else min

    const float* xbase = x + (size_t)b * CI * HIN * WIN_;

    float s1 = 0.f, s2 = 0.f;

    for (int j = 0; j < 32; ++j) {
        // ---- stage input rows (slot = row % 6) ----
        __syncthreads();
        if (j == 0) {
            for (int k = t; k < 6 * CI * 32; k += 256) {
                int cc4 = k & 31, ci = (k >> 5) & 7, rr = k >> 8;
                ((float4*)&xb[rr][ci][0])[cc4] =
                    ((const float4*)(xbase + (ci * HIN + rr) * WIN_))[cc4];
            }
        } else {
            const int r0    = 4 * j + 2;
            const int nrows = (j < 31) ? 4 : 2;
            for (int k = t; k < nrows * CI * 32; k += 256) {
                int cc4 = k & 31, ci = (k >> 5) & 7, rr = k >> 8;
                int gr  = r0 + rr;
                ((float4*)&xb[gr % 6][ci][0])[cc4] =
                    ((const float4*)(xbase + (ci * HIN + gr) * WIN_))[cc4];
            }
        }
        __syncthreads();

        // ---- conv: 2 rows (r0h, r0h+1) x 4 cols (col0..col0+3), 1 channel ----
        const int r0h = 4 * j + 2 * rh;
        if (r0h < HO_) {
            float acc[2][4] = {{0.f,0.f,0.f,0.f},{0.f,0.f,0.f,0.f}};
            int sl[4];
            #pragma unroll
            for (int kr = 0; kr < 4; ++kr) sl[kr] = (r0h + kr) % 6;

            #pragma unroll
            for (int ci = 0; ci < CI; ++ci) {
                float xv[4][6];
                #pragma unroll
                for (int kr = 0; kr < 4; ++kr) {
                    float4 v4 = *(const float4*)&xb[sl[kr]][ci][col0];
                    xv[kr][0] = v4.x; xv[kr][1] = v4.y;
                    xv[kr][2] = v4.z; xv[kr][3] = v4.w;
                    // cols col0+4, col0+5: for cg==31 this reads past the row
                    // (garbage inside LDS) — only feeds outputs 126/127 which
                    // never enter stats or pooling.
                    float2 v2 = *(const float2*)&xb[sl[kr]][ci][col0 + 4];
                    xv[kr][4] = v2.x; xv[kr][5] = v2.y;
                }
                #pragma unroll
                for (int kh = 0; kh < 3; ++kh)
                #pragma unroll
                for (int kw = 0; kw < 3; ++kw) {
                    float wv = w[ci * 9 + kh * 3 + kw];
                    #pragma unroll
                    for (int q = 0; q < 4; ++q) {
                        acc[0][q] = fmaf(wv, xv[kh][kw + q],     acc[0][q]);
                        acc[1][q] = fmaf(wv, xv[kh + 1][kw + q], acc[1][q]);
                    }
                }
            }

            // bias + stats (valid outputs only: cg==31 -> cols 124,125 only)
            #pragma unroll
            for (int r = 0; r < 2; ++r)
            #pragma unroll
            for (int q = 0; q < 4; ++q) {
                float v = acc[r][q] + bias;
                acc[r][q] = v;
                if ((cg < 31) | (q < 2)) { s1 += v; s2 = fmaf(v, v, s2); }
            }

            // pool: reduce own 2x4, combine rh pair via shfl_xor(4)
            if (j < PW) {
                float e;
                if (pos) {
                    e = fmaxf(fmaxf(fmaxf(acc[0][0], acc[0][1]), fmaxf(acc[0][2], acc[0][3])),
                              fmaxf(fmaxf(acc[1][0], acc[1][1]), fmaxf(acc[1][2], acc[1][3])));
                    e = fmaxf(e, __shfl_xor(e, 4));
                } else {
                    e = fminf(fminf(fminf(acc[0][0], acc[0][1]), fminf(acc[0][2], acc[0][3])),
                              fminf(fminf(acc[1][0], acc[1][1]), fminf(acc[1][2], acc[1][3])));
                    e = fminf(e, __shfl_xor(e, 4));
                }
                if (rh == 0 && cg < PW) wpool[c][j][cg] = e;
            }
        }
    }

    // ---- GroupNorm stats reduction ----
    #pragma unroll
    for (int off = 1; off < 64; off <<= 1) {
        s1 += __shfl_xor(s1, off);
        s2 += __shfl_xor(s2, off);
    }
    if ((t & 63) == 0) { redbuf[t >> 6][0] = s1; redbuf[t >> 6][1] = s2; }
    __syncthreads();
    if (t == 0) {
        float S1 = 0.f, S2 = 0.f;
        #pragma unroll
        for (int wv = 0; wv < 4; ++wv) { S1 += redbuf[wv][0]; S2 += redbuf[wv][1]; }
        const float invN = 1.0f / (float)(CPG * HO_ * HO_);
        float mean = S1 * invN;
        float var  = S2 * invN - mean * mean;
        statbuf[0] = mean;
        statbuf[1] = rsqrtf(var + EPS);
    }
    __syncthreads();
    const float mean = statbuf[0];
    const float inv  = statbuf[1];

    // ---- epilogue: affine on kept extreme + clamp + store ----
    for (int i = t; i < CPG * PW * PW; i += 256) {
        int cc  = i / (PW * PW);
        int rem = i - cc * (PW * PW);
        int pi  = rem / PW;
        int pj  = rem - pi * PW;
        int cox = co0 + cc;
        float A  = inv * gnw[cox] * scl[cox];
        float Bv = (gnb[cox] - mean * inv * gnw[cox]) * scl[cox];
        float v  = fmaf(A, wpool[cc][pi][pj], Bv);
        v = fminf(fmaxf(v, 0.f), 1.f);
        out[(((size_t)b * CO + cox) * PW + pi) * PW + pj] = v;
    }
}

extern "C" void kernel_launch(void* const* d_in, const int* in_sizes, int n_in,
                              void* d_out, int out_size, void* d_ws, size_t ws_size,
                              hipStream_t stream) {
    const float* x   = (const float*)d_in[0];
    const float* cw  = (const float*)d_in[1];
    const float* cb  = (const float*)d_in[2];
    const float* gnw = (const float*)d_in[3];
    const float* gnb = (const float*)d_in[4];
    const float* scl = (const float*)d_in[5];
    float* out = (float*)d_out;
    (void)d_ws; (void)ws_size; (void)in_sizes; (void)n_in; (void)out_size;

    fused_conv_gn_pool<<<dim3(128 * 16), dim3(256), 0, stream>>>(
        x, cw, cb, gnw, gnb, scl, out);
}

// Round 3
// 611.589 us; speedup vs baseline: 1.1705x; 1.1705x over previous
//
#include <hip/hip_runtime.h>

// Fused Conv3x3(8->64) + bias + GroupNorm(16) + scale + MaxPool4x4 + clamp
// Block = (batch, group). Thread = (channel c=t&3, row-half rh=(t>>2)&1,
// col-group cg=t>>3 covering cols 4cg..4cg+3). Weights live in registers
// (72/thread, SROA-safe scalar fill + fully-unrolled constant indexing).
// Pool commutes with the per-channel affine: sign(A_c)=sign(gnw_c*scale_c)
// is known up-front (rsqrt>0), so keep only max (A>=0) or min (A<0) of the
// raw conv output per 4x4 window; GN applied to the single kept extreme.

constexpr int CI   = 8;
constexpr int CO   = 64;
constexpr int HIN  = 128;
constexpr int WIN_ = 128;
constexpr int HO_  = 126;
constexpr int CPG  = 4;    // channels per group
constexpr int PW   = 31;   // pooled H/W
constexpr float EPS = 1e-5f;

__global__ __launch_bounds__(256, 2)
void fused_conv_gn_pool(const float* __restrict__ x,
                        const float* __restrict__ cw,
                        const float* __restrict__ cb,
                        const float* __restrict__ gnw,
                        const float* __restrict__ gnb,
                        const float* __restrict__ scl,
                        float* __restrict__ out)
{
    __shared__ float xb[6][CI][WIN_];        // rolling input rows  24576 B
    __shared__ float wpool[CPG][PW][PW];     // window extremes     15376 B
    __shared__ float redbuf[4][2];
    __shared__ float statbuf[2];

    const int t   = threadIdx.x;
    const int b   = blockIdx.x >> 4;
    const int g   = blockIdx.x & 15;
    const int co0 = g * CPG;

    const int c    = t & 3;          // channel within group
    const int rh   = (t >> 2) & 1;   // which row-pair of the 4-row window
    const int cg   = t >> 3;         // col group: cols 4cg..4cg+3
    const int col0 = cg * 4;
    const int co   = co0 + c;

    // ---- per-thread channel weights in registers (72 floats) ----
    // Scalar-typed unrolled fill: every subsequent access uses a
    // compile-time-constant index, so SROA keeps the array in VGPRs.
    float w[72];
    {
        const float* wp = cw + (size_t)co * (CI * 9);
        #pragma unroll
        for (int i = 0; i < 72; ++i) w[i] = wp[i];
    }
    const float bias = cb[co];
    const bool  pos  = (gnw[co] * scl[co] >= 0.f);   // keep max if true, else min

    const float* xbase = x + (size_t)b * CI * HIN * WIN_;

    float s1 = 0.f, s2 = 0.f;

    for (int j = 0; j < 32; ++j) {
        // ---- stage input rows (slot = row % 6) ----
        __syncthreads();
        if (j == 0) {
            for (int k = t; k < 6 * CI * 32; k += 256) {
                int cc4 = k & 31, ci = (k >> 5) & 7, rr = k >> 8;
                ((float4*)&xb[rr][ci][0])[cc4] =
                    ((const float4*)(xbase + (ci * HIN + rr) * WIN_))[cc4];
            }
        } else {
            const int r0    = 4 * j + 2;
            const int nrows = (j < 31) ? 4 : 2;
            for (int k = t; k < nrows * CI * 32; k += 256) {
                int cc4 = k & 31, ci = (k >> 5) & 7, rr = k >> 8;
                int gr  = r0 + rr;
                ((float4*)&xb[gr % 6][ci][0])[cc4] =
                    ((const float4*)(xbase + (ci * HIN + gr) * WIN_))[cc4];
            }
        }
        __syncthreads();

        // ---- conv: 2 rows (r0h, r0h+1) x 4 cols (col0..), 1 channel ----
        const int r0h = 4 * j + 2 * rh;
        if (r0h < HO_) {
            float acc0[4] = {0.f, 0.f, 0.f, 0.f};
            float acc1[4] = {0.f, 0.f, 0.f, 0.f};

            // 4 row base pointers for this j (runtime slot, hoisted once)
            const float* rb[4];
            #pragma unroll
            for (int d = 0; d < 4; ++d) rb[d] = &xb[(r0h + d) % 6][0][col0];

            #pragma unroll
            for (int ci = 0; ci < CI; ++ci) {
                #pragma unroll
                for (int d = 0; d < 4; ++d) {
                    // load one staged input row segment: 6 floats
                    // (cols col0..col0+5; for cg==31 the last 2 are garbage
                    //  inside LDS -> only feed excluded outputs 126/127)
                    const float* p = rb[d] + ci * WIN_;
                    float4 v4 = *(const float4*)p;
                    float2 v2 = *(const float2*)(p + 4);
                    float xv[6];
                    xv[0] = v4.x; xv[1] = v4.y; xv[2] = v4.z; xv[3] = v4.w;
                    xv[4] = v2.x; xv[5] = v2.y;

                    if (d < 3) {            // weight row d -> output row 0
                        #pragma unroll
                        for (int kw = 0; kw < 3; ++kw) {
                            float wv = w[ci * 9 + d * 3 + kw];
                            #pragma unroll
                            for (int q = 0; q < 4; ++q)
                                acc0[q] = fmaf(wv, xv[kw + q], acc0[q]);
                        }
                    }
                    if (d >= 1) {           // weight row d-1 -> output row 1
                        #pragma unroll
                        for (int kw = 0; kw < 3; ++kw) {
                            float wv = w[ci * 9 + (d - 1) * 3 + kw];
                            #pragma unroll
                            for (int q = 0; q < 4; ++q)
                                acc1[q] = fmaf(wv, xv[kw + q], acc1[q]);
                        }
                    }
                }
            }

            // bias + stats (valid outputs only: cg==31 -> cols 124,125 only)
            #pragma unroll
            for (int q = 0; q < 4; ++q) {
                float v0 = acc0[q] + bias;
                float v1 = acc1[q] + bias;
                acc0[q] = v0; acc1[q] = v1;
                if ((cg < 31) | (q < 2)) {
                    s1 += v0 + v1;
                    s2 = fmaf(v0, v0, fmaf(v1, v1, s2));
                }
            }

            // pool: reduce own 2x4, combine rh pair via shfl_xor(4)
            if (j < PW) {
                float e;
                if (pos) {
                    e = fmaxf(fmaxf(fmaxf(acc0[0], acc0[1]), fmaxf(acc0[2], acc0[3])),
                              fmaxf(fmaxf(acc1[0], acc1[1]), fmaxf(acc1[2], acc1[3])));
                    e = fmaxf(e, __shfl_xor(e, 4));
                } else {
                    e = fminf(fminf(fminf(acc0[0], acc0[1]), fminf(acc0[2], acc0[3])),
                              fminf(fminf(acc1[0], acc1[1]), fminf(acc1[2], acc1[3])));
                    e = fminf(e, __shfl_xor(e, 4));
                }
                if (rh == 0 && cg < PW) wpool[c][j][cg] = e;
            }
        }
    }

    // ---- GroupNorm stats reduction ----
    #pragma unroll
    for (int off = 1; off < 64; off <<= 1) {
        s1 += __shfl_xor(s1, off);
        s2 += __shfl_xor(s2, off);
    }
    if ((t & 63) == 0) { redbuf[t >> 6][0] = s1; redbuf[t >> 6][1] = s2; }
    __syncthreads();
    if (t == 0) {
        float S1 = 0.f, S2 = 0.f;
        #pragma unroll
        for (int wv = 0; wv < 4; ++wv) { S1 += redbuf[wv][0]; S2 += redbuf[wv][1]; }
        const float invN = 1.0f / (float)(CPG * HO_ * HO_);
        float mean = S1 * invN;
        float var  = S2 * invN - mean * mean;
        statbuf[0] = mean;
        statbuf[1] = rsqrtf(var + EPS);
    }
    __syncthreads();
    const float mean = statbuf[0];
    const float inv  = statbuf[1];

    // ---- epilogue: affine on kept extreme + clamp + store ----
    for (int i = t; i < CPG * PW * PW; i += 256) {
        int cc  = i / (PW * PW);
        int rem = i - cc * (PW * PW);
        int pi  = rem / PW;
        int pj  = rem - pi * PW;
        int cox = co0 + cc;
        float A  = inv * gnw[cox] * scl[cox];
        float Bv = (gnb[cox] - mean * inv * gnw[cox]) * scl[cox];
        float v  = fmaf(A, wpool[cc][pi][pj], Bv);
        v = fminf(fmaxf(v, 0.f), 1.f);
        out[(((size_t)b * CO + cox) * PW + pi) * PW + pj] = v;
    }
}

extern "C" void kernel_launch(void* const* d_in, const int* in_sizes, int n_in,
                              void* d_out, int out_size, void* d_ws, size_t ws_size,
                              hipStream_t stream) {
    const float* x   = (const float*)d_in[0];
    const float* cw  = (const float*)d_in[1];
    const float* cb  = (const float*)d_in[2];
    const float* gnw = (const float*)d_in[3];
    const float* gnb = (const float*)d_in[4];
    const float* scl = (const float*)d_in[5];
    float* out = (float*)d_out;
    (void)d_ws; (void)ws_size; (void)in_sizes; (void)n_in; (void)out_size;

    fused_conv_gn_pool<<<dim3(128 * 16), dim3(256), 0, stream>>>(
        x, cw, cb, gnw, gnb, scl, out);
}